// Round 1
// baseline (387.608 us; speedup 1.0000x reference)
//
#include <hip/hip_runtime.h>

// ECE (expected calibration error) over N=32M samples, n_bins=10.
// Strategy: memory-bound streaming pass (384 MB reads) with per-thread
// register-resident 10-bin accumulators (no atomics in the hot loop),
// wave shuffle-reduce -> block LDS reduce -> per-block partials in d_ws,
// then a tiny single-block finalize kernel in f64.

#define NBLK 2048
#define TPB  256
#define MAXB 256

// --- per-element binning, bit-exact vs jnp.linspace(0,1,nb+1) + searchsorted(left) ---
// boundaries[j] = (float)j * (1.0f/nb) computed in f32; bin = #{ j in 1..nb : b_j < conf }.

__global__ __launch_bounds__(TPB) void ece_partial(
    const float* __restrict__ conf, const int* __restrict__ pred,
    const int* __restrict__ lab, const int* __restrict__ nbins_p,
    int n, int cap,
    unsigned* __restrict__ ws_cnt, unsigned* __restrict__ ws_acc,
    float* __restrict__ ws_conf)
{
  const int nb = nbins_p[0];
  const int tid = blockIdx.x * blockDim.x + threadIdx.x;
  const int nthreads = gridDim.x * blockDim.x;

  __shared__ unsigned s_ca[TPB / 64][10];
  __shared__ float    s_cs[TPB / 64][10];
  // generic-path privatized histogram
  __shared__ unsigned g_cnt[MAXB];
  __shared__ unsigned g_acc[MAXB];
  __shared__ float    g_conf[MAXB];

  if (nb == 10 && cap >= 10) {
    // ---------------- fast path: nb == 10, register accumulators ----------------
    unsigned ca[10];  // (cnt << 16) | acc, per-thread (<= 64 elements each, no overflow)
    float    cs[10];
#pragma unroll
    for (int j = 0; j < 10; ++j) { ca[j] = 0u; cs[j] = 0.0f; }

    const int n4 = n >> 2;
    const float4* c4 = (const float4*)conf;
    const int4*   p4 = (const int4*)pred;
    const int4*   l4 = (const int4*)lab;

    for (int i = tid; i < n4; i += nthreads) {
      float4 c = c4[i];
      int4   p = p4[i];
      int4   l = l4[i];
      float cc[4] = {c.x, c.y, c.z, c.w};
      int   ok[4] = {p.x == l.x, p.y == l.y, p.z == l.z, p.w == l.w};
#pragma unroll
      for (int e = 0; e < 4; ++e) {
        float v = cc[e];
        int bin = 0;
#pragma unroll
        for (int j = 1; j <= 10; ++j) bin += ((float)j * 0.1f < v) ? 1 : 0;
        if (bin > 9) bin = 9;
#pragma unroll
        for (int j = 0; j < 10; ++j) {
          bool m = (bin == j);
          ca[j] += m ? (0x10000u | (unsigned)ok[e]) : 0u;
          cs[j] += m ? v : 0.0f;
        }
      }
    }
    // scalar tail (n % 4)
    for (int i = (n4 << 2) + tid; i < n; i += nthreads) {
      float v = conf[i];
      int okk = (pred[i] == lab[i]);
      int bin = 0;
#pragma unroll
      for (int j = 1; j <= 10; ++j) bin += ((float)j * 0.1f < v) ? 1 : 0;
      if (bin > 9) bin = 9;
#pragma unroll
      for (int j = 0; j < 10; ++j) {
        bool m = (bin == j);
        ca[j] += m ? (0x10000u | (unsigned)okk) : 0u;
        cs[j] += m ? v : 0.0f;
      }
    }

    // wave (64-lane) butterfly reduce, then cross-wave via LDS
    const int lane = threadIdx.x & 63;
    const int wv   = threadIdx.x >> 6;
#pragma unroll
    for (int j = 0; j < 10; ++j) {
      unsigned a = ca[j];
      float    s = cs[j];
#pragma unroll
      for (int d = 32; d > 0; d >>= 1) {
        a += __shfl_xor(a, d, 64);
        s += __shfl_xor(s, d, 64);
      }
      if (lane == 0) { s_ca[wv][j] = a; s_cs[wv][j] = s; }
    }
    __syncthreads();
    if (threadIdx.x < 10) {
      unsigned tot = 0; float tc = 0.0f;
#pragma unroll
      for (int w = 0; w < TPB / 64; ++w) { tot += s_ca[w][threadIdx.x]; tc += s_cs[w][threadIdx.x]; }
      const int o = threadIdx.x * gridDim.x + blockIdx.x;  // layout [bin][block]
      ws_cnt[o]  = tot >> 16;
      ws_acc[o]  = tot & 0xFFFFu;
      ws_conf[o] = tc;
    }
  } else {
    // ---------------- generic fallback: LDS-atomic privatized histogram ----------------
    int nbc = nb < 1 ? 1 : nb;
    if (nbc > MAXB) nbc = MAXB;
    if (nbc > cap) nbc = (cap < 1) ? 1 : cap;
    for (int j = threadIdx.x; j < nbc; j += blockDim.x) { g_cnt[j] = 0u; g_acc[j] = 0u; g_conf[j] = 0.0f; }
    __syncthreads();
    const float delta = 1.0f / (float)nb;
    for (int i = tid; i < n; i += nthreads) {
      float v = conf[i];
      int okk = (pred[i] == lab[i]);
      int bin = (int)(v * (float)nb);
      if (bin > nb - 1) bin = nb - 1;
      if (bin < 0) bin = 0;
      while (bin < nb - 1 && (float)(bin + 1) * delta < v) ++bin;
      while (bin > 0 && !((float)bin * delta < v)) --bin;
      if (bin > nbc - 1) bin = nbc - 1;
      atomicAdd(&g_cnt[bin], 1u);
      atomicAdd(&g_acc[bin], (unsigned)okk);
      atomicAdd(&g_conf[bin], v);
    }
    __syncthreads();
    for (int j = threadIdx.x; j < nbc; j += blockDim.x) {
      ws_cnt[j * gridDim.x + blockIdx.x]  = g_cnt[j];
      ws_acc[j * gridDim.x + blockIdx.x]  = g_acc[j];
      ws_conf[j * gridDim.x + blockIdx.x] = g_conf[j];
    }
  }
}

__global__ __launch_bounds__(640) void ece_final(
    const unsigned* __restrict__ ws_cnt, const unsigned* __restrict__ ws_acc,
    const float* __restrict__ ws_conf, const int* __restrict__ nbins_p,
    int n, int cap, float* __restrict__ out)
{
  int nb = nbins_p[0];
  if (nb < 1) nb = 1;
  int mx = cap < MAXB ? cap : MAXB;
  if (nb > mx) nb = mx;
  const int wv   = threadIdx.x >> 6;  // 10 waves, one bin each (stride 10 for generic nb)
  const int lane = threadIdx.x & 63;
  __shared__ double terms[MAXB];
  for (int j = threadIdx.x; j < MAXB; j += blockDim.x) terms[j] = 0.0;
  __syncthreads();
  for (int bin = wv; bin < nb; bin += 10) {
    unsigned long long cnt = 0, acc = 0;
    double cs = 0.0;
    for (int b = lane; b < NBLK; b += 64) {
      cnt += ws_cnt[bin * NBLK + b];
      acc += ws_acc[bin * NBLK + b];
      cs  += (double)ws_conf[bin * NBLK + b];
    }
#pragma unroll
    for (int d = 32; d > 0; d >>= 1) {
      cnt += __shfl_xor(cnt, d, 64);
      acc += __shfl_xor(acc, d, 64);
      cs  += __shfl_xor(cs, d, 64);
    }
    if (lane == 0) {
      double t = 0.0;
      if (cnt > 0) {
        double dc = (double)cnt;
        t = fabs(cs / dc - (double)acc / dc) * (dc / (double)n);
      }
      terms[bin] = t;
    }
  }
  __syncthreads();
  if (threadIdx.x == 0) {
    double e = 0.0;
    for (int j = 0; j < nb; ++j) e += terms[j];
    out[0] = (float)e;
  }
}

extern "C" void kernel_launch(void* const* d_in, const int* in_sizes, int n_in,
                              void* d_out, int out_size, void* d_ws, size_t ws_size,
                              hipStream_t stream) {
  const float* conf = (const float*)d_in[0];
  const int*   pred = (const int*)d_in[1];
  const int*   lab  = (const int*)d_in[2];
  const int*   nbp  = (const int*)d_in[3];
  const int n = in_sizes[0];

  // partition workspace into 3 partial arrays of [cap_bins][NBLK] u32/f32
  size_t per = ws_size / 3;
  int cap = (int)(per / ((size_t)NBLK * sizeof(unsigned)));
  if (cap > MAXB) cap = MAXB;
  unsigned* ws_cnt = (unsigned*)d_ws;
  unsigned* ws_acc = (unsigned*)((char*)d_ws + (size_t)cap * NBLK * sizeof(unsigned));
  float*    ws_conf = (float*)((char*)d_ws + 2ull * (size_t)cap * NBLK * sizeof(unsigned));

  ece_partial<<<NBLK, TPB, 0, stream>>>(conf, pred, lab, nbp, n, cap, ws_cnt, ws_acc, ws_conf);
  ece_final<<<1, 640, 0, stream>>>(ws_cnt, ws_acc, ws_conf, nbp, n, cap, (float*)d_out);
}

// Round 3
// 363.314 us; speedup vs baseline: 1.0669x; 1.0669x over previous
//
#include <hip/hip_runtime.h>

// ECE over N=32M samples, n_bins=10.
// Round 2 (resubmit; round-2 bench was an infra timeout): fix latency-bound
// partial kernel (VGPR 32 -> register-starved, serialized loads). Software-
// pipelined loads + launch_bounds(256,4) + cheap direct binning. Vectorized
// finalize kernel.

#define NBLK 2048
#define TPB  256
#define MAXB 256

// Bit-exact binning vs jnp.linspace(0,1,11)[1:] + searchsorted(left):
// boundaries b_j = (float)j * 0.1f (f32); bin = #{ j in 1..10 : b_j < v }, clamped to [0,9].
// Computed as e = trunc(v*10) with +/-1 correction against exact b_e, b_{e+1}.
#define PROC4(c, p, l)                                                        \
  {                                                                           \
    float vv[4] = {(c).x, (c).y, (c).z, (c).w};                               \
    int   oo[4] = {(p).x == (l).x, (p).y == (l).y, (p).z == (l).z,            \
                   (p).w == (l).w};                                           \
    _Pragma("unroll")                                                         \
    for (int e = 0; e < 4; ++e) {                                             \
      float v  = vv[e];                                                       \
      int   ei = (int)(v * 10.0f);                                            \
      float fe = (float)ei;                                                   \
      float b0 = fe * 0.1f;                                                   \
      float b1 = (fe + 1.0f) * 0.1f;                                          \
      int bin = ei + ((b1 < v) ? 1 : 0) - ((b0 < v) ? 0 : 1);                 \
      bin = bin < 0 ? 0 : (bin > 9 ? 9 : bin);                                \
      unsigned inc = 0x10000u | (unsigned)oo[e];                              \
      _Pragma("unroll")                                                       \
      for (int j = 0; j < 10; ++j) {                                          \
        bool m = (bin == j);                                                  \
        ca[j] += m ? inc : 0u;                                                \
        cs[j] += m ? v : 0.0f;                                                \
      }                                                                       \
    }                                                                         \
  }

__global__ __launch_bounds__(TPB, 4) void ece_partial(
    const float* __restrict__ conf, const int* __restrict__ pred,
    const int* __restrict__ lab, const int* __restrict__ nbins_p,
    int n, int cap,
    unsigned* __restrict__ ws_cnt, unsigned* __restrict__ ws_acc,
    float* __restrict__ ws_conf)
{
  const int nb = nbins_p[0];
  const int tid = blockIdx.x * blockDim.x + threadIdx.x;
  const int nthreads = gridDim.x * blockDim.x;

  __shared__ unsigned s_ca[TPB / 64][10];
  __shared__ float    s_cs[TPB / 64][10];
  __shared__ unsigned g_cnt[MAXB];
  __shared__ unsigned g_acc[MAXB];
  __shared__ float    g_conf[MAXB];

  if (nb == 10 && cap >= 10) {
    // ---------------- fast path: nb == 10, register accumulators ----------------
    unsigned ca[10];  // (cnt << 16) | acc  (per-thread elems ~64 -> no overflow)
    float    cs[10];
#pragma unroll
    for (int j = 0; j < 10; ++j) { ca[j] = 0u; cs[j] = 0.0f; }

    const int n4 = n >> 2;
    const float4* c4 = (const float4*)conf;
    const int4*   p4 = (const int4*)pred;
    const int4*   l4 = (const int4*)lab;

    const int iters = n4 / nthreads;  // uniform across threads

    if (iters > 0) {
      // software pipeline: keep next iteration's 3 vec4 loads in flight
      int i = tid;
      float4 c = c4[i];
      int4   p = p4[i];
      int4   l = l4[i];
      for (int k = 1; k < iters; ++k) {
        const int inx = i + nthreads;
        float4 cN = c4[inx];
        int4   pN = p4[inx];
        int4   lN = l4[inx];
        PROC4(c, p, l);
        c = cN; p = pN; l = lN; i = inx;
      }
      PROC4(c, p, l);
    }
    // residual vec4 (when n4 % nthreads != 0)
    for (int i = iters * nthreads + tid; i < n4; i += nthreads) {
      float4 c = c4[i];
      int4   p = p4[i];
      int4   l = l4[i];
      PROC4(c, p, l);
    }
    // scalar tail (n % 4)
    for (int i = (n4 << 2) + tid; i < n; i += nthreads) {
      float v = conf[i];
      int okk = (pred[i] == lab[i]);
      int   ei = (int)(v * 10.0f);
      float fe = (float)ei;
      float b0 = fe * 0.1f;
      float b1 = (fe + 1.0f) * 0.1f;
      int bin = ei + ((b1 < v) ? 1 : 0) - ((b0 < v) ? 0 : 1);
      bin = bin < 0 ? 0 : (bin > 9 ? 9 : bin);
#pragma unroll
      for (int j = 0; j < 10; ++j) {
        bool m = (bin == j);
        ca[j] += m ? (0x10000u | (unsigned)okk) : 0u;
        cs[j] += m ? v : 0.0f;
      }
    }

    // wave butterfly reduce -> cross-wave LDS reduce -> per-block partial
    const int lane = threadIdx.x & 63;
    const int wv   = threadIdx.x >> 6;
#pragma unroll
    for (int j = 0; j < 10; ++j) {
      unsigned a = ca[j];
      float    s = cs[j];
#pragma unroll
      for (int d = 32; d > 0; d >>= 1) {
        a += __shfl_xor(a, d, 64);
        s += __shfl_xor(s, d, 64);
      }
      if (lane == 0) { s_ca[wv][j] = a; s_cs[wv][j] = s; }
    }
    __syncthreads();
    if (threadIdx.x < 10) {
      unsigned tot = 0; float tc = 0.0f;
#pragma unroll
      for (int w = 0; w < TPB / 64; ++w) { tot += s_ca[w][threadIdx.x]; tc += s_cs[w][threadIdx.x]; }
      const int o = threadIdx.x * gridDim.x + blockIdx.x;  // [bin][block]
      ws_cnt[o]  = tot >> 16;
      ws_acc[o]  = tot & 0xFFFFu;
      ws_conf[o] = tc;
    }
  } else {
    // ---------------- generic fallback: LDS-atomic privatized histogram ----------------
    int nbc = nb < 1 ? 1 : nb;
    if (nbc > MAXB) nbc = MAXB;
    if (nbc > cap) nbc = (cap < 1) ? 1 : cap;
    for (int j = threadIdx.x; j < nbc; j += blockDim.x) { g_cnt[j] = 0u; g_acc[j] = 0u; g_conf[j] = 0.0f; }
    __syncthreads();
    const float delta = 1.0f / (float)nb;
    for (int i = tid; i < n; i += nthreads) {
      float v = conf[i];
      int okk = (pred[i] == lab[i]);
      int bin = (int)(v * (float)nb);
      if (bin > nb - 1) bin = nb - 1;
      if (bin < 0) bin = 0;
      while (bin < nb - 1 && (float)(bin + 1) * delta < v) ++bin;
      while (bin > 0 && !((float)bin * delta < v)) --bin;
      if (bin > nbc - 1) bin = nbc - 1;
      atomicAdd(&g_cnt[bin], 1u);
      atomicAdd(&g_acc[bin], (unsigned)okk);
      atomicAdd(&g_conf[bin], v);
    }
    __syncthreads();
    for (int j = threadIdx.x; j < nbc; j += blockDim.x) {
      ws_cnt[j * gridDim.x + blockIdx.x]  = g_cnt[j];
      ws_acc[j * gridDim.x + blockIdx.x]  = g_acc[j];
      ws_conf[j * gridDim.x + blockIdx.x] = g_conf[j];
    }
  }
}

__global__ __launch_bounds__(640) void ece_final(
    const unsigned* __restrict__ ws_cnt, const unsigned* __restrict__ ws_acc,
    const float* __restrict__ ws_conf, const int* __restrict__ nbins_p,
    int n, int cap, float* __restrict__ out)
{
  int nb = nbins_p[0];
  if (nb < 1) nb = 1;
  int mx = cap < MAXB ? cap : MAXB;
  if (nb > mx) nb = mx;
  const int wv   = threadIdx.x >> 6;
  const int lane = threadIdx.x & 63;
  __shared__ double terms[MAXB];
  for (int j = threadIdx.x; j < MAXB; j += blockDim.x) terms[j] = 0.0;
  __syncthreads();

  if (nb == 10) {
    // one wave per bin, vectorized coalesced reduction of 2048 partials
    const int bin = wv;  // 10 waves
    const uint4*  c4 = (const uint4*)(ws_cnt  + (size_t)bin * NBLK);
    const uint4*  a4 = (const uint4*)(ws_acc  + (size_t)bin * NBLK);
    const float4* f4 = (const float4*)(ws_conf + (size_t)bin * NBLK);
    unsigned cnt = 0, acc = 0;
    double cs = 0.0;
#pragma unroll
    for (int it = 0; it < NBLK / 256; ++it) {  // 8 iters of 64 lanes * 16B
      uint4  a = c4[it * 64 + lane];
      uint4  b = a4[it * 64 + lane];
      float4 f = f4[it * 64 + lane];
      cnt += a.x + a.y + a.z + a.w;
      acc += b.x + b.y + b.z + b.w;
      cs  += ((double)f.x + (double)f.y) + ((double)f.z + (double)f.w);
    }
#pragma unroll
    for (int d = 32; d > 0; d >>= 1) {
      cnt += __shfl_xor(cnt, d, 64);
      acc += __shfl_xor(acc, d, 64);
      cs  += __shfl_xor(cs, d, 64);
    }
    if (lane == 0) {
      double t = 0.0;
      if (cnt > 0) {
        double dc = (double)cnt;
        t = fabs(cs / dc - (double)acc / dc) * (dc / (double)n);
      }
      terms[bin] = t;
    }
  } else {
    for (int bin = wv; bin < nb; bin += 10) {
      unsigned long long cnt = 0, acc = 0;
      double cs = 0.0;
      for (int b = lane; b < NBLK; b += 64) {
        cnt += ws_cnt[bin * NBLK + b];
        acc += ws_acc[bin * NBLK + b];
        cs  += (double)ws_conf[bin * NBLK + b];
      }
#pragma unroll
      for (int d = 32; d > 0; d >>= 1) {
        cnt += __shfl_xor(cnt, d, 64);
        acc += __shfl_xor(acc, d, 64);
        cs  += __shfl_xor(cs, d, 64);
      }
      if (lane == 0) {
        double t = 0.0;
        if (cnt > 0) {
          double dc = (double)cnt;
          t = fabs(cs / dc - (double)acc / dc) * (dc / (double)n);
        }
        terms[bin] = t;
      }
    }
  }
  __syncthreads();
  if (threadIdx.x == 0) {
    double e = 0.0;
    for (int j = 0; j < nb; ++j) e += terms[j];
    out[0] = (float)e;
  }
}

extern "C" void kernel_launch(void* const* d_in, const int* in_sizes, int n_in,
                              void* d_out, int out_size, void* d_ws, size_t ws_size,
                              hipStream_t stream) {
  const float* conf = (const float*)d_in[0];
  const int*   pred = (const int*)d_in[1];
  const int*   lab  = (const int*)d_in[2];
  const int*   nbp  = (const int*)d_in[3];
  const int n = in_sizes[0];

  size_t per = ws_size / 3;
  int cap = (int)(per / ((size_t)NBLK * sizeof(unsigned)));
  if (cap > MAXB) cap = MAXB;
  unsigned* ws_cnt = (unsigned*)d_ws;
  unsigned* ws_acc = (unsigned*)((char*)d_ws + (size_t)cap * NBLK * sizeof(unsigned));
  float*    ws_conf = (float*)((char*)d_ws + 2ull * (size_t)cap * NBLK * sizeof(unsigned));

  ece_partial<<<NBLK, TPB, 0, stream>>>(conf, pred, lab, nbp, n, cap, ws_cnt, ws_acc, ws_conf);
  ece_final<<<1, 640, 0, stream>>>(ws_cnt, ws_acc, ws_conf, nbp, n, cap, (float*)d_out);
}